// Round 4
// baseline (1157.287 us; speedup 1.0000x reference)
//
#include <hip/hip_runtime.h>
#include <hip/hip_bf16.h>

#define SEQ   8192
#define EMB   256
#define TAGS  10
#define PFD   8   // prefetch depth in the scan

static_assert(SEQ % PFD == 0, "unroll");

constexpr float INV2PI  = 0.15915494309189535f;   // 1/(2*pi)
constexpr float NLOG2E  = -1.4426950408889634f;   // -log2(e)

// ---------------- DPP helpers (all VALU-speed, no LDS pipe) ----------------
// quad_perm rotations within each 4-lane quad: dest lane i reads quad-lane sel[i].
// rot1: [1,2,3,0] = 0x39, rot2: [2,3,0,1] = 0x4E, rot3: [3,0,1,2] = 0x93.
// row_shl:n (0x100+n): lane i reads lane i+n within its 16-lane row.
// row_shr:n (0x110+n): lane i reads lane i-n. (GPUOpen cross-lane doc semantics.)
#define QR1   0x39
#define QR2   0x4E
#define QR3   0x93
#define SHL4  0x104
#define SHL8  0x108
#define SHL12 0x10C
#define SHR4  0x114
#define SHR8  0x118
#define SHR12 0x11C

template<int CTRL>
__device__ __forceinline__ float fdpp(float x) {
    return __builtin_bit_cast(float,
        __builtin_amdgcn_update_dpp(0, __builtin_bit_cast(int, x),
                                    CTRL, 0xF, 0xF, true));
}

// a is in REVOLUTIONS (pre-scaled by 1/2pi). v_cos_f32: D = cos(S0 * 2pi),
// reduce with fract first (ISA doc).
__device__ __forceinline__ float cos_rev(float a) {
    float r = a - floorf(a);
#if __has_builtin(__builtin_amdgcn_cosf)
    return __builtin_amdgcn_cosf(r);
#else
    return __cosf(r * 6.2831853071795864f);
#endif
}
__device__ __forceinline__ float exp2h(float x) {
#if __has_builtin(__builtin_amdgcn_exp2f)
    return __builtin_amdgcn_exp2f(x);
#else
    return exp2f(x);
#endif
}
__device__ __forceinline__ float rcph(float x) {
#if __has_builtin(__builtin_amdgcn_rcpf)
    return __builtin_amdgcn_rcpf(x);
#else
    return 1.0f / x;
#endif
}

// ---------------- Kernel 1: pre[t][g*4+w] = (x@Wg + bg + pg)/(2pi) ----------
// One wave per token. lane = chunk(2b)<<4 | gw(4b); each lane dots a 64-elem
// chunk of the embed row against column (g,w); reduce over the 4 chunks.
__global__ __launch_bounds__(64) void k_pre(
    const int*   __restrict__ sentence, const float* __restrict__ embed,
    const float* __restrict__ Wf, const float* __restrict__ bf,
    const float* __restrict__ Wi, const float* __restrict__ bi,
    const float* __restrict__ Wu, const float* __restrict__ bu,
    const float* __restrict__ Wo, const float* __restrict__ bo,
    const float* __restrict__ pf, const float* __restrict__ ppi,
    const float* __restrict__ pu, const float* __restrict__ po,
    float* __restrict__ pre)
{
    const int t     = blockIdx.x;
    const int gw    = threadIdx.x & 15;
    const int chunk = threadIdx.x >> 4;
    const int g = gw >> 2, w = gw & 3;

    const float* Wg = (g == 0) ? Wf : (g == 1) ? Wi : (g == 2) ? Wu : Wo;
    const long long row = sentence[t];
    const float* eb = embed + row * (long long)EMB + chunk * 64;
    const float* wb = Wg + chunk * 64 * 4 + w;   // W[k][w] at W[k*4+w]

    float s = 0.f;
#pragma unroll
    for (int i = 0; i < 64; ++i)
        s = fmaf(eb[i], wb[i * 4], s);

    s += __shfl_xor(s, 16, 64);
    s += __shfl_xor(s, 32, 64);

    if (threadIdx.x < 16) {
        const float* bg = (g == 0) ? bf : (g == 1) ? bi : (g == 2) ? bu : bo;
        const float* pg = (g == 0) ? pf : (g == 1) ? ppi : (g == 2) ? pu : po;
        pre[t * 16 + gw] = (s + bg[w] + pg[w]) * INV2PI;
    }
}

// ---------------- Kernel 2: the serial scan (single wave) -------------------
// Logical lane L = g*4 + w (g: 0=f,1=i,2=u,3=o). Lanes 16..63 replicate
// lanes 0..15 exactly (all indexing via tid&15), so there is no divergence and
// all DPP row/quad patterns mirror per 16-lane row.
__global__ __launch_bounds__(64) void k_scan(
    const float* __restrict__ pre,
    const float* __restrict__ Wf, const float* __restrict__ Wi,
    const float* __restrict__ Wu, const float* __restrict__ Wo,
    float* __restrict__ outs)
{
    const int lane = threadIdx.x & 15;
    const int w = lane & 3, g = lane >> 2;

    const float* Wg = (g == 0) ? Wf : (g == 1) ? Wi : (g == 2) ? Wu : Wo;
    // h-register r holds hx_{(w+r)&3}; match coefficients accordingly.
    const float c0 = Wg[(EMB + ((w + 0) & 3)) * 4 + w] * INV2PI;
    const float c1 = Wg[(EMB + ((w + 1) & 3)) * 4 + w] * INV2PI;
    const float c2 = Wg[(EMB + ((w + 2) & 3)) * 4 + w] * INV2PI;
    const float c3 = Wg[(EMB + ((w + 3) & 3)) * 4 + w] * INV2PI;

    // gate nonlinearity: u -> tanh(q) = 2*sigmoid(2q)-1, else sigmoid(q)
    const bool  isU  = (g == 2);
    const float cexp = isU ? 2.f * NLOG2E : NLOG2E;  // exp2(cexp*q) = exp(-m*q)
    const float ymul = isU ? 2.f : 1.f;
    const float yadd = isU ? -1.f : 0.f;

    // qlayer subsets: q0=z1z2z3, q1=z0z1, q2=z0z1z2, q3=z0z1z2z3
    const int smask = (w == 0) ? 0xE : (w == 1) ? 0x3 : (w == 2) ? 0x7 : 0xF;
    const bool i0 = (smask >> ((w + 0) & 3)) & 1;
    const bool i1 = (smask >> ((w + 1) & 3)) & 1;
    const bool i2 = (smask >> ((w + 2) & 3)) & 1;
    const bool i3 = (smask >> ((w + 3) & 3)) & 1;

    float buf[PFD];
#pragma unroll
    for (int d = 0; d < PFD; ++d) buf[d] = pre[d * 16 + lane];

    float h0 = 0.f, h1 = 0.f, h2 = 0.f, h3 = 0.f, cx = 0.f;

    for (int t0 = 0; t0 < SEQ; t0 += PFD) {
#pragma unroll
        for (int d = 0; d < PFD; ++d) {
            const int t = t0 + d;
            const float pv = buf[d];
            // prefetch t+PFD (pre buffer is padded by PFD*16; tail values unused)
            buf[d] = pre[(t + PFD) * 16 + lane];

            // a in revolutions
            float a = pv;
            a = fmaf(h0, c0, a);
            a = fmaf(h1, c1, a);
            a = fmaf(h2, c2, a);
            a = fmaf(h3, c3, a);
            const float z = cos_rev(a);

            // all four z's of this gate via quad rotations
            const float z1 = fdpp<QR1>(z);
            const float z2 = fdpp<QR2>(z);
            const float z3 = fdpp<QR3>(z);
            const float m0 = i0 ? z  : 1.f;
            const float m1 = i1 ? z1 : 1.f;
            const float m2 = i2 ? z2 : 1.f;
            const float m3 = i3 ? z3 : 1.f;
            const float q  = (m0 * m1) * (m2 * m3);

            // activation (sigmoid or tanh via per-lane constants)
            const float eq = exp2h(q * cexp);
            const float y  = fmaf(ymul, rcph(1.f + eq), yadd);

            // gather f,i,u,o across gates (stride 4 in the 16-lane row)
            const float s4  = fdpp<SHL4 >(y);
            const float s8  = fdpp<SHL8 >(y);
            const float s12 = fdpp<SHL12>(y);
            const float r4  = fdpp<SHR4 >(y);
            const float r8  = fdpp<SHR8 >(y);
            const float r12 = fdpp<SHR12>(y);
            const float Fg = (g == 0) ? y   : (g == 1) ? r4 : (g == 2) ? r8 : r12;
            const float Ig = (g == 0) ? s4  : (g == 1) ? y  : (g == 2) ? r4 : r8;
            const float Ug = (g == 0) ? s8  : (g == 1) ? s4 : (g == 2) ? y  : r4;
            const float Og = (g == 0) ? s12 : (g == 1) ? s8 : (g == 2) ? s4 : y;

            cx = fmaf(Fg, cx, Ig * Ug);
            const float e2 = exp2h(cx * (2.f * NLOG2E));
            const float th = fmaf(2.f, rcph(1.f + e2), -1.f);
            const float h  = Og * th;

            if (threadIdx.x < 4) outs[t * 4 + w] = h;  // lanes 0..3 own wires 0..3

            h0 = h;
            h1 = fdpp<QR1>(h);
            h2 = fdpp<QR2>(h);
            h3 = fdpp<QR3>(h);
        }
    }
}

// ---------------- Kernel 3: logits + log_softmax ----------------------------
__global__ __launch_bounds__(256) void k_out(
    const float* __restrict__ outs, const float* __restrict__ Wt,
    const float* __restrict__ bt, float* __restrict__ out)
{
    const int t = blockIdx.x * blockDim.x + threadIdx.x;
    if (t >= SEQ) return;
    const float h0 = outs[t * 4 + 0], h1 = outs[t * 4 + 1];
    const float h2 = outs[t * 4 + 2], h3 = outs[t * 4 + 3];

    float lg[TAGS];
    float m = -1e30f;
#pragma unroll
    for (int j = 0; j < TAGS; ++j) {
        float v = bt[j];
        v = fmaf(h0, Wt[0 * TAGS + j], v);
        v = fmaf(h1, Wt[1 * TAGS + j], v);
        v = fmaf(h2, Wt[2 * TAGS + j], v);
        v = fmaf(h3, Wt[3 * TAGS + j], v);
        lg[j] = v;
        m = fmaxf(m, v);
    }
    float s = 0.f;
#pragma unroll
    for (int j = 0; j < TAGS; ++j) s += expf(lg[j] - m);
    const float ls = logf(s) + m;
#pragma unroll
    for (int j = 0; j < TAGS; ++j) out[t * TAGS + j] = lg[j] - ls;
}

extern "C" void kernel_launch(void* const* d_in, const int* in_sizes, int n_in,
                              void* d_out, int out_size, void* d_ws, size_t ws_size,
                              hipStream_t stream) {
    const int*   sentence = (const int*)  d_in[0];
    const float* embed    = (const float*)d_in[1];
    const float* Wf  = (const float*)d_in[2];
    const float* bf  = (const float*)d_in[3];
    const float* Wi  = (const float*)d_in[4];
    const float* bi  = (const float*)d_in[5];
    const float* Wu  = (const float*)d_in[6];
    const float* bu  = (const float*)d_in[7];
    const float* Wo  = (const float*)d_in[8];
    const float* bo  = (const float*)d_in[9];
    const float* pf  = (const float*)d_in[10];
    const float* ppi = (const float*)d_in[11];
    const float* pu  = (const float*)d_in[12];
    const float* po  = (const float*)d_in[13];
    const float* Wt  = (const float*)d_in[14];
    const float* bt  = (const float*)d_in[15];

    float* pre  = (float*)d_ws;                    // (SEQ+PFD)*16 floats (padded)
    float* outs = pre + (SEQ + PFD) * 16;          // SEQ*4 floats

    k_pre<<<SEQ, 64, 0, stream>>>(sentence, embed, Wf, bf, Wi, bi, Wu, bu,
                                  Wo, bo, pf, ppi, pu, po, pre);
    k_scan<<<1, 64, 0, stream>>>(pre, Wf, Wi, Wu, Wo, outs);
    k_out<<<(SEQ + 255) / 256, 256, 0, stream>>>(outs, Wt, bt, (float*)d_out);
}

// Round 5
// 1140.571 us; speedup vs baseline: 1.0147x; 1.0147x over previous
//
#include <hip/hip_runtime.h>
#include <hip/hip_bf16.h>

#define SEQ   8192
#define EMB   256
#define TAGS  10
#define PFD   8   // prefetch depth in the scan

static_assert(SEQ % PFD == 0, "unroll");

constexpr float INV2PI  = 0.15915494309189535f;   // 1/(2*pi)

// ---------------- DPP helpers (all VALU-speed, no LDS pipe) ----------------
// quad_perm rotations within each 4-lane quad: dest lane i reads quad-lane sel[i].
// rot1: [1,2,3,0] = 0x39, rot2: [2,3,0,1] = 0x4E, rot3: [3,0,1,2] = 0x93.
// row_shl:n (0x100+n): lane i reads lane i+n within its 16-lane row.
// row_shr:n (0x110+n): lane i reads lane i-n.  (proven mappings — absmax 0.0)
#define QR1   0x39
#define QR2   0x4E
#define QR3   0x93
#define SHL4  0x104
#define SHL8  0x108
#define SHL12 0x10C
#define SHR4  0x114
#define SHR8  0x118
#define SHR12 0x11C

template<int CTRL>
__device__ __forceinline__ float fdpp(float x) {
    return __builtin_bit_cast(float,
        __builtin_amdgcn_update_dpp(0, __builtin_bit_cast(int, x),
                                    CTRL, 0xF, 0xF, true));
}

// a is in REVOLUTIONS (pre-scaled by 1/2pi). v_cos_f32: D = cos(S0 * 2pi),
// reduce with fract first (ISA doc). v_fract_f32 = S0 - floor(S0).
__device__ __forceinline__ float fract_f(float a) {
#if __has_builtin(__builtin_amdgcn_fractf)
    return __builtin_amdgcn_fractf(a);
#else
    return a - floorf(a);
#endif
}
__device__ __forceinline__ float cos_rev(float a) {
    float r = fract_f(a);
#if __has_builtin(__builtin_amdgcn_cosf)
    return __builtin_amdgcn_cosf(r);
#else
    return __cosf(r * 6.2831853071795864f);
#endif
}

// deg-7 odd poly for tanh on [-1,1], max err ~2e-4 (interp at x=.25,.55,.8,.95)
#define K1  0.99988000f
#define K3 -0.33064200f
#define K5  0.11945370f
#define K7 -0.02727870f
// deg-11 odd poly for tanh on [-2.15,2.15], max err ~7e-4 inside |x|<=2.1
#define B0  0.99958010f
#define B1 -0.32717320f
#define B2  0.11471900f
#define B3 -0.03006680f
#define B4  0.00466450f
#define B5 -0.00030650f

// ---------------- Kernel 1: pre[t][g*4+w] = (x@Wg + bg + pg)/(2pi) ----------
__global__ __launch_bounds__(64) void k_pre(
    const int*   __restrict__ sentence, const float* __restrict__ embed,
    const float* __restrict__ Wf, const float* __restrict__ bf,
    const float* __restrict__ Wi, const float* __restrict__ bi,
    const float* __restrict__ Wu, const float* __restrict__ bu,
    const float* __restrict__ Wo, const float* __restrict__ bo,
    const float* __restrict__ pf, const float* __restrict__ ppi,
    const float* __restrict__ pu, const float* __restrict__ po,
    float* __restrict__ pre)
{
    const int t     = blockIdx.x;
    const int gw    = threadIdx.x & 15;
    const int chunk = threadIdx.x >> 4;
    const int g = gw >> 2, w = gw & 3;

    const float* Wg = (g == 0) ? Wf : (g == 1) ? Wi : (g == 2) ? Wu : Wo;
    const long long row = sentence[t];
    const float* eb = embed + row * (long long)EMB + chunk * 64;
    const float* wb = Wg + chunk * 64 * 4 + w;   // W[k][w] at W[k*4+w]

    float s = 0.f;
#pragma unroll
    for (int i = 0; i < 64; ++i)
        s = fmaf(eb[i], wb[i * 4], s);

    s += __shfl_xor(s, 16, 64);
    s += __shfl_xor(s, 32, 64);

    if (threadIdx.x < 16) {
        const float* bg = (g == 0) ? bf : (g == 1) ? bi : (g == 2) ? bu : bo;
        const float* pg = (g == 0) ? pf : (g == 1) ? ppi : (g == 2) ? pu : po;
        pre[t * 16 + gw] = (s + bg[w] + pg[w]) * INV2PI;
    }
}

// ---------------- Kernel 2: the serial scan (single wave) -------------------
// Logical lane L = g*4 + w (g: 0=f,1=i,2=u,3=o). Lanes 16..63 replicate
// lanes 0..15 (all indexing via tid&15) -> zero divergence, DPP rows mirror.
__global__ __launch_bounds__(64) void k_scan(
    const float* __restrict__ pre,
    const float* __restrict__ Wf, const float* __restrict__ Wi,
    const float* __restrict__ Wu, const float* __restrict__ Wo,
    float* __restrict__ outs)
{
    const int lane = threadIdx.x & 15;
    const int w = lane & 3, g = lane >> 2;

    const float* Wg = (g == 0) ? Wf : (g == 1) ? Wi : (g == 2) ? Wu : Wo;
    // h-register r holds hx_{(w+r)&3}; match coefficients accordingly.
    const float c0 = Wg[(EMB + ((w + 0) & 3)) * 4 + w] * INV2PI;
    const float c1 = Wg[(EMB + ((w + 1) & 3)) * 4 + w] * INV2PI;
    const float c2 = Wg[(EMB + ((w + 2) & 3)) * 4 + w] * INV2PI;
    const float c3 = Wg[(EMB + ((w + 3) & 3)) * 4 + w] * INV2PI;

    // gate nonlinearity via unified tanh-poly T:
    //   f,i,o: sigmoid(q) = 0.5 + 0.5*T(0.5*q)   (T arg in [-0.5,0.5])
    //   u:     tanh(q)    = T(q)                  (T arg in [-1,1])
    const bool  isU = (g == 2);
    const float alp = isU ? 1.0f : 0.5f;   // input scale
    const float bet = isU ? 1.0f : 0.5f;   // output scale
    const float gam = isU ? 0.0f : 0.5f;   // output offset

    // qlayer subsets: q0=z1z2z3, q1=z0z1, q2=z0z1z2, q3=z0z1z2z3
    const int smask = (w == 0) ? 0xE : (w == 1) ? 0x3 : (w == 2) ? 0x7 : 0xF;
    const bool i0 = (smask >> ((w + 0) & 3)) & 1;
    const bool i1 = (smask >> ((w + 1) & 3)) & 1;
    const bool i2 = (smask >> ((w + 2) & 3)) & 1;
    const bool i3 = (smask >> ((w + 3) & 3)) & 1;

    float buf[PFD];
#pragma unroll
    for (int d = 0; d < PFD; ++d) buf[d] = pre[d * 16 + lane];

    float h0 = 0.f, h1 = 0.f, h2 = 0.f, h3 = 0.f, cx = 0.f;

    for (int t0 = 0; t0 < SEQ; t0 += PFD) {
#pragma unroll
        for (int d = 0; d < PFD; ++d) {
            const int t = t0 + d;
            const float pv = buf[d];
            // prefetch t+PFD (pre buffer padded by PFD*16; tail values unused)
            buf[d] = pre[(t + PFD) * 16 + lane];

            // a in revolutions (tree-ish dot for shorter chain)
            const float a0 = fmaf(h0, c0, pv);
            const float a1 = fmaf(h1, c1, a0);
            const float m2d = h2 * c2;
            const float a2 = fmaf(h3, c3, m2d);
            const float a  = a1 + a2;
            const float z  = cos_rev(a);

            // all four z's of this gate via quad rotations
            const float z1 = fdpp<QR1>(z);
            const float z2 = fdpp<QR2>(z);
            const float z3 = fdpp<QR3>(z);
            const float m0 = i0 ? z  : 1.f;
            const float m1 = i1 ? z1 : 1.f;
            const float m2 = i2 ? z2 : 1.f;
            const float m3 = i3 ? z3 : 1.f;
            const float q  = (m0 * m1) * (m2 * m3);   // in [-1,1]

            // activation via deg-7 odd tanh poly (0 trans ops)
            const float x   = q * alp;
            const float u   = x * x;
            const float u2p = u * u;
            const float cA  = fmaf(K7, u, K5);
            const float cB  = fmaf(K3, u, K1);
            const float dd  = fmaf(cA, u2p, cB);
            const float v   = x * dd;                 // = T(x)
            const float y   = fmaf(bet, v, gam);

            // gather f,i,u,o across gates (stride 4 in the 16-lane row)
            const float s4  = fdpp<SHL4 >(y);
            const float s8  = fdpp<SHL8 >(y);
            const float s12 = fdpp<SHL12>(y);
            const float r4  = fdpp<SHR4 >(y);
            const float r8  = fdpp<SHR8 >(y);
            const float r12 = fdpp<SHR12>(y);
            const float Fg = (g == 0) ? y   : (g == 1) ? r4 : (g == 2) ? r8 : r12;
            const float Ig = (g == 0) ? s4  : (g == 1) ? y  : (g == 2) ? r4 : r8;
            const float Ug = (g == 0) ? s8  : (g == 1) ? s4 : (g == 2) ? y  : r4;
            const float Og = (g == 0) ? s12 : (g == 1) ? s8 : (g == 2) ? s4 : y;

            cx = fmaf(Fg, cx, Ig * Ug);               // |cx| <= 2.071

            // tanh(cx) via deg-11 odd poly on [-2.15,2.15] (0 trans ops)
            const float cu  = cx * cx;
            const float cu2 = cu * cu;
            const float cu4 = cu2 * cu2;
            const float e0  = fmaf(B1, cu, B0);
            const float e1  = fmaf(B3, cu, B2);
            const float e2  = fmaf(B5, cu, B4);
            const float f0  = fmaf(e1, cu2, e0);
            const float f1  = fmaf(e2, cu4, f0);
            const float th  = cx * f1;
            const float h   = Og * th;

            if (threadIdx.x < 4) outs[t * 4 + w] = h;  // lanes 0..3 own wires

            h0 = h;
            h1 = fdpp<QR1>(h);
            h2 = fdpp<QR2>(h);
            h3 = fdpp<QR3>(h);
        }
    }
}

// ---------------- Kernel 3: logits + log_softmax ----------------------------
__global__ __launch_bounds__(256) void k_out(
    const float* __restrict__ outs, const float* __restrict__ Wt,
    const float* __restrict__ bt, float* __restrict__ out)
{
    const int t = blockIdx.x * blockDim.x + threadIdx.x;
    if (t >= SEQ) return;
    const float h0 = outs[t * 4 + 0], h1 = outs[t * 4 + 1];
    const float h2 = outs[t * 4 + 2], h3 = outs[t * 4 + 3];

    float lg[TAGS];
    float m = -1e30f;
#pragma unroll
    for (int j = 0; j < TAGS; ++j) {
        float v = bt[j];
        v = fmaf(h0, Wt[0 * TAGS + j], v);
        v = fmaf(h1, Wt[1 * TAGS + j], v);
        v = fmaf(h2, Wt[2 * TAGS + j], v);
        v = fmaf(h3, Wt[3 * TAGS + j], v);
        lg[j] = v;
        m = fmaxf(m, v);
    }
    float s = 0.f;
#pragma unroll
    for (int j = 0; j < TAGS; ++j) s += expf(lg[j] - m);
    const float ls = logf(s) + m;
#pragma unroll
    for (int j = 0; j < TAGS; ++j) out[t * TAGS + j] = lg[j] - ls;
}

extern "C" void kernel_launch(void* const* d_in, const int* in_sizes, int n_in,
                              void* d_out, int out_size, void* d_ws, size_t ws_size,
                              hipStream_t stream) {
    const int*   sentence = (const int*)  d_in[0];
    const float* embed    = (const float*)d_in[1];
    const float* Wf  = (const float*)d_in[2];
    const float* bf  = (const float*)d_in[3];
    const float* Wi  = (const float*)d_in[4];
    const float* bi  = (const float*)d_in[5];
    const float* Wu  = (const float*)d_in[6];
    const float* bu  = (const float*)d_in[7];
    const float* Wo  = (const float*)d_in[8];
    const float* bo  = (const float*)d_in[9];
    const float* pf  = (const float*)d_in[10];
    const float* ppi = (const float*)d_in[11];
    const float* pu  = (const float*)d_in[12];
    const float* po  = (const float*)d_in[13];
    const float* Wt  = (const float*)d_in[14];
    const float* bt  = (const float*)d_in[15];

    float* pre  = (float*)d_ws;                    // (SEQ+PFD)*16 floats (padded)
    float* outs = pre + (SEQ + PFD) * 16;          // SEQ*4 floats

    k_pre<<<SEQ, 64, 0, stream>>>(sentence, embed, Wf, bf, Wi, bi, Wu, bu,
                                  Wo, bo, pf, ppi, pu, po, pre);
    k_scan<<<1, 64, 0, stream>>>(pre, Wf, Wi, Wu, Wo, outs);
    k_out<<<(SEQ + 255) / 256, 256, 0, stream>>>(outs, Wt, bt, (float*)d_out);
}

// Round 7
// 52.227 us; speedup vs baseline: 22.1586x; 21.8386x over previous
//
#include <hip/hip_runtime.h>
#include <hip/hip_bf16.h>

#define SEQ   8192
#define EMB   256
#define TAGS  10
#define PFD   8     // prefetch depth in the scan
#define CHUNK 32    // outputs per chunk (one wave each)
#define WARM  128   // warmup steps from zero state (contraction: f <= 0.731)

static_assert(SEQ % CHUNK == 0, "chunks tile SEQ");
static_assert(CHUNK % PFD == 0 && WARM % CHUNK == 0, "unroll");

constexpr float INV2PI  = 0.15915494309189535f;   // 1/(2*pi)

// ---------------- DPP helpers (all VALU-speed, no LDS pipe) ----------------
// quad_perm rot1 [1,2,3,0]=0x39, rot2=0x4E, rot3=0x93.
// row_shl:n (0x100+n): lane i reads lane i+n in its 16-lane row.
// row_shr:n (0x110+n): lane i reads lane i-n.  (proven mappings — absmax-exact)
#define QR1   0x39
#define QR2   0x4E
#define QR3   0x93
#define SHL4  0x104
#define SHL8  0x108
#define SHL12 0x10C
#define SHR4  0x114
#define SHR8  0x118
#define SHR12 0x11C

template<int CTRL>
__device__ __forceinline__ float fdpp(float x) {
    return __builtin_bit_cast(float,
        __builtin_amdgcn_update_dpp(0, __builtin_bit_cast(int, x),
                                    CTRL, 0xF, 0xF, true));
}

__device__ __forceinline__ float fract_f(float a) {
#if __has_builtin(__builtin_amdgcn_fractf)
    return __builtin_amdgcn_fractf(a);
#else
    return a - floorf(a);
#endif
}
// a in REVOLUTIONS; v_cos_f32: D = cos(S0 * 2pi), reduce with fract first.
__device__ __forceinline__ float cos_rev(float a) {
    float r = fract_f(a);
#if __has_builtin(__builtin_amdgcn_cosf)
    return __builtin_amdgcn_cosf(r);
#else
    return __cosf(r * 6.2831853071795864f);
#endif
}

// deg-7 odd poly for tanh on [-1,1], max err ~2e-4
#define K1  0.99988000f
#define K3 -0.33064200f
#define K5  0.11945370f
#define K7 -0.02727870f
// deg-11 odd poly for tanh on [-2.15,2.15], max err ~7e-4
#define B0  0.99958010f
#define B1 -0.32717320f
#define B2  0.11471900f
#define B3 -0.03006680f
#define B4  0.00466450f
#define B5 -0.00030650f

// ---------------- Kernel 1: pre[t][g*4+w] = (x@Wg + bg + pg)/(2pi) ----------
__global__ __launch_bounds__(64) void k_pre(
    const int*   __restrict__ sentence, const float* __restrict__ embed,
    const float* __restrict__ Wf, const float* __restrict__ bf,
    const float* __restrict__ Wi, const float* __restrict__ bi,
    const float* __restrict__ Wu, const float* __restrict__ bu,
    const float* __restrict__ Wo, const float* __restrict__ bo,
    const float* __restrict__ pf, const float* __restrict__ ppi,
    const float* __restrict__ pu, const float* __restrict__ po,
    float* __restrict__ pre)
{
    const int t     = blockIdx.x;
    const int gw    = threadIdx.x & 15;
    const int chunk = threadIdx.x >> 4;
    const int g = gw >> 2, w = gw & 3;

    const float* Wg = (g == 0) ? Wf : (g == 1) ? Wi : (g == 2) ? Wu : Wo;
    const long long row = sentence[t];
    const float* eb = embed + row * (long long)EMB + chunk * 64;
    const float* wb = Wg + chunk * 64 * 4 + w;   // W[k][w] at W[k*4+w]

    float s = 0.f;
#pragma unroll
    for (int i = 0; i < 64; ++i)
        s = fmaf(eb[i], wb[i * 4], s);

    s += __shfl_xor(s, 16, 64);
    s += __shfl_xor(s, 32, 64);

    if (threadIdx.x < 16) {
        const float* bg = (g == 0) ? bf : (g == 1) ? bi : (g == 2) ? bu : bo;
        const float* pg = (g == 0) ? pf : (g == 1) ? ppi : (g == 2) ? pu : po;
        pre[t * 16 + gw] = (s + bg[w] + pg[w]) * INV2PI;
    }
}

// ---------------- Kernel 2: chunked scan with warmup ------------------------
// blockIdx.x = chunk c; outputs t in [c*CHUNK, (c+1)*CHUNK).
// Chunks start WARM steps early from zero state, CLAMPED at 0 (early chunks
// run their exact prefix from the true init — no approximation there).
// Contraction (f<=0.731) makes the warmup state error at the first stored
// step < 1e-5 for the clamped-at-WARM chunks.
// Lane layout identical to the proven serial version: L = g*4+w in each
// 16-lane row, rows replicate -> zero divergence, DPP rows mirror.
__global__ __launch_bounds__(64) void k_scan(
    const float* __restrict__ pre,
    const float* __restrict__ Wf, const float* __restrict__ Wi,
    const float* __restrict__ Wu, const float* __restrict__ Wo,
    float* __restrict__ outs)
{
    const int lane = threadIdx.x & 15;
    const int w = lane & 3, g = lane >> 2;

    const int c       = blockIdx.x;
    const int start   = c * CHUNK;                       // first stored step
    const int t_begin = (start >= WARM) ? (start - WARM) : 0;  // CLAMPED (fix)
    const int t_end   = start + CHUNK;
    const int nsteps  = t_end - t_begin;                 // multiple of CHUNK

    const float* Wg = (g == 0) ? Wf : (g == 1) ? Wi : (g == 2) ? Wu : Wo;
    // h-register r holds hx_{(w+r)&3}; match coefficients accordingly.
    const float c0 = Wg[(EMB + ((w + 0) & 3)) * 4 + w] * INV2PI;
    const float c1 = Wg[(EMB + ((w + 1) & 3)) * 4 + w] * INV2PI;
    const float c2 = Wg[(EMB + ((w + 2) & 3)) * 4 + w] * INV2PI;
    const float c3 = Wg[(EMB + ((w + 3) & 3)) * 4 + w] * INV2PI;

    // f,i,o: sigmoid(q) = 0.5 + 0.5*T(0.5*q); u: tanh(q) = T(q)
    const bool  isU = (g == 2);
    const float alp = isU ? 1.0f : 0.5f;
    const float bet = isU ? 1.0f : 0.5f;
    const float gam = isU ? 0.0f : 0.5f;

    // qlayer subsets: q0=z1z2z3, q1=z0z1, q2=z0z1z2, q3=z0z1z2z3
    const int smask = (w == 0) ? 0xE : (w == 1) ? 0x3 : (w == 2) ? 0x7 : 0xF;
    const bool i0 = (smask >> ((w + 0) & 3)) & 1;
    const bool i1 = (smask >> ((w + 1) & 3)) & 1;
    const bool i2 = (smask >> ((w + 2) & 3)) & 1;
    const bool i3 = (smask >> ((w + 3) & 3)) & 1;

    float buf[PFD];
#pragma unroll
    for (int d = 0; d < PFD; ++d) buf[d] = pre[(t_begin + d) * 16 + lane];

    float h0 = 0.f, h1 = 0.f, h2 = 0.f, h3 = 0.f, cx = 0.f;

    for (int s0 = 0; s0 < nsteps; s0 += PFD) {
#pragma unroll
        for (int d = 0; d < PFD; ++d) {
            const int t = t_begin + s0 + d;
            const float pv = buf[d];
            // prefetch t+PFD (pre padded by PFD*16 floats; tail values unused)
            buf[d] = pre[(t + PFD) * 16 + lane];

            // a in revolutions
            const float a0 = fmaf(h0, c0, pv);
            const float a1 = fmaf(h1, c1, a0);
            const float m2d = h2 * c2;
            const float a2 = fmaf(h3, c3, m2d);
            const float a  = a1 + a2;
            const float z  = cos_rev(a);

            // all four z's of this gate via quad rotations
            const float z1 = fdpp<QR1>(z);
            const float z2 = fdpp<QR2>(z);
            const float z3 = fdpp<QR3>(z);
            const float m0 = i0 ? z  : 1.f;
            const float m1 = i1 ? z1 : 1.f;
            const float m2 = i2 ? z2 : 1.f;
            const float m3 = i3 ? z3 : 1.f;
            const float q  = (m0 * m1) * (m2 * m3);   // in [-1,1]

            // activation via deg-7 odd tanh poly
            const float x   = q * alp;
            const float u   = x * x;
            const float u2p = u * u;
            const float cA  = fmaf(K7, u, K5);
            const float cB  = fmaf(K3, u, K1);
            const float dd  = fmaf(cA, u2p, cB);
            const float v   = x * dd;                 // = T(x)
            const float y   = fmaf(bet, v, gam);

            // gather f,i,u,o across gates (stride 4 in the 16-lane row)
            const float s4  = fdpp<SHL4 >(y);
            const float s8  = fdpp<SHL8 >(y);
            const float s12 = fdpp<SHL12>(y);
            const float r4  = fdpp<SHR4 >(y);
            const float r8  = fdpp<SHR8 >(y);
            const float r12 = fdpp<SHR12>(y);
            const float Fg = (g == 0) ? y   : (g == 1) ? r4 : (g == 2) ? r8 : r12;
            const float Ig = (g == 0) ? s4  : (g == 1) ? y  : (g == 2) ? r4 : r8;
            const float Ug = (g == 0) ? s8  : (g == 1) ? s4 : (g == 2) ? y  : r4;
            const float Og = (g == 0) ? s12 : (g == 1) ? s8 : (g == 2) ? s4 : y;

            cx = fmaf(Fg, cx, Ig * Ug);               // |cx| <= 2.071

            // tanh(cx) via deg-11 odd poly
            const float cu  = cx * cx;
            const float cu2 = cu * cu;
            const float cu4 = cu2 * cu2;
            const float e0  = fmaf(B1, cu, B0);
            const float e1  = fmaf(B3, cu, B2);
            const float e2  = fmaf(B5, cu, B4);
            const float f0  = fmaf(e1, cu2, e0);
            const float f1  = fmaf(e2, cu4, f0);
            const float th  = cx * f1;
            const float h   = Og * th;

            // store only inside the owned window (wave-uniform branch)
            if (t >= start && threadIdx.x < 4) outs[t * 4 + w] = h;

            h0 = h;
            h1 = fdpp<QR1>(h);
            h2 = fdpp<QR2>(h);
            h3 = fdpp<QR3>(h);
        }
    }
}

// ---------------- Kernel 3: logits + log_softmax ----------------------------
__global__ __launch_bounds__(256) void k_out(
    const float* __restrict__ outs, const float* __restrict__ Wt,
    const float* __restrict__ bt, float* __restrict__ out)
{
    const int t = blockIdx.x * blockDim.x + threadIdx.x;
    if (t >= SEQ) return;
    const float h0 = outs[t * 4 + 0], h1 = outs[t * 4 + 1];
    const float h2 = outs[t * 4 + 2], h3 = outs[t * 4 + 3];

    float lg[TAGS];
    float m = -1e30f;
#pragma unroll
    for (int j = 0; j < TAGS; ++j) {
        float v = bt[j];
        v = fmaf(h0, Wt[0 * TAGS + j], v);
        v = fmaf(h1, Wt[1 * TAGS + j], v);
        v = fmaf(h2, Wt[2 * TAGS + j], v);
        v = fmaf(h3, Wt[3 * TAGS + j], v);
        lg[j] = v;
        m = fmaxf(m, v);
    }
    float s = 0.f;
#pragma unroll
    for (int j = 0; j < TAGS; ++j) s += expf(lg[j] - m);
    const float ls = logf(s) + m;
#pragma unroll
    for (int j = 0; j < TAGS; ++j) out[t * TAGS + j] = lg[j] - ls;
}

extern "C" void kernel_launch(void* const* d_in, const int* in_sizes, int n_in,
                              void* d_out, int out_size, void* d_ws, size_t ws_size,
                              hipStream_t stream) {
    const int*   sentence = (const int*)  d_in[0];
    const float* embed    = (const float*)d_in[1];
    const float* Wf  = (const float*)d_in[2];
    const float* bf  = (const float*)d_in[3];
    const float* Wi  = (const float*)d_in[4];
    const float* bi  = (const float*)d_in[5];
    const float* Wu  = (const float*)d_in[6];
    const float* bu  = (const float*)d_in[7];
    const float* Wo  = (const float*)d_in[8];
    const float* bo  = (const float*)d_in[9];
    const float* pf  = (const float*)d_in[10];
    const float* ppi = (const float*)d_in[11];
    const float* pu  = (const float*)d_in[12];
    const float* po  = (const float*)d_in[13];
    const float* Wt  = (const float*)d_in[14];
    const float* bt  = (const float*)d_in[15];

    float* pre  = (float*)d_ws;                    // (SEQ+PFD)*16 floats (padded)
    float* outs = pre + (SEQ + PFD) * 16;          // SEQ*4 floats

    k_pre<<<SEQ, 64, 0, stream>>>(sentence, embed, Wf, bf, Wi, bi, Wu, bu,
                                  Wo, bo, pf, ppi, pu, po, pre);
    k_scan<<<SEQ / CHUNK, 64, 0, stream>>>(pre, Wf, Wi, Wu, Wo, outs);
    k_out<<<(SEQ + 255) / 256, 256, 0, stream>>>(outs, Wt, bt, (float*)d_out);
}

// Round 8
// 38.099 us; speedup vs baseline: 30.3758x; 1.3708x over previous
//
#include <hip/hip_runtime.h>
#include <hip/hip_bf16.h>

#define SEQ   8192
#define EMB   256
#define TAGS  10
#define PFD   8     // prefetch depth in the scan
#define CHUNK 16    // outputs per chunk (one wave each)
#define WARM  48    // warmup steps from zero state (worst-case rho<=0.78 -> 7e-6)

static_assert(SEQ % CHUNK == 0, "chunks tile SEQ");
static_assert(CHUNK % PFD == 0 && WARM % PFD == 0, "unroll");

constexpr float INV2PI  = 0.15915494309189535f;   // 1/(2*pi)

// ---------------- DPP helpers (all VALU-speed, no LDS pipe) ----------------
// quad_perm rot1 [1,2,3,0]=0x39, rot2=0x4E, rot3=0x93.
// row_shl:n (0x100+n): lane i reads lane i+n in its 16-lane row.
// row_shr:n (0x110+n): lane i reads lane i-n.  (proven mappings — absmax-exact)
#define QR1   0x39
#define QR2   0x4E
#define QR3   0x93
#define SHL4  0x104
#define SHL8  0x108
#define SHL12 0x10C
#define SHR4  0x114
#define SHR8  0x118
#define SHR12 0x11C

template<int CTRL>
__device__ __forceinline__ float fdpp(float x) {
    return __builtin_bit_cast(float,
        __builtin_amdgcn_update_dpp(0, __builtin_bit_cast(int, x),
                                    CTRL, 0xF, 0xF, true));
}

__device__ __forceinline__ float fract_f(float a) {
#if __has_builtin(__builtin_amdgcn_fractf)
    return __builtin_amdgcn_fractf(a);
#else
    return a - floorf(a);
#endif
}
// a in REVOLUTIONS; v_cos_f32: D = cos(S0 * 2pi), reduce with fract first.
__device__ __forceinline__ float cos_rev(float a) {
    float r = fract_f(a);
#if __has_builtin(__builtin_amdgcn_cosf)
    return __builtin_amdgcn_cosf(r);
#else
    return __cosf(r * 6.2831853071795864f);
#endif
}

// deg-7 odd poly for tanh on [-1,1], max err ~2e-4
#define K1  0.99988000f
#define K3 -0.33064200f
#define K5  0.11945370f
#define K7 -0.02727870f
// deg-11 odd poly for tanh on [-2.15,2.15], max err ~7e-4
#define B0  0.99958010f
#define B1 -0.32717320f
#define B2  0.11471900f
#define B3 -0.03006680f
#define B4  0.00466450f
#define B5 -0.00030650f

// ---------------- Kernel 1: pre[t][g*4+w] = (x@Wg + bg + pg)/(2pi) ----------
// One wave per token. lane = chunk(2b)<<4 | gw(4b). float4 e-loads, 4
// independent accumulators (chain depth 16 instead of 64).
__global__ __launch_bounds__(64) void k_pre(
    const int*   __restrict__ sentence, const float* __restrict__ embed,
    const float* __restrict__ Wf, const float* __restrict__ bf,
    const float* __restrict__ Wi, const float* __restrict__ bi,
    const float* __restrict__ Wu, const float* __restrict__ bu,
    const float* __restrict__ Wo, const float* __restrict__ bo,
    const float* __restrict__ pf, const float* __restrict__ ppi,
    const float* __restrict__ pu, const float* __restrict__ po,
    float* __restrict__ pre)
{
    const int t     = blockIdx.x;
    const int gw    = threadIdx.x & 15;
    const int chunk = threadIdx.x >> 4;
    const int g = gw >> 2, w = gw & 3;

    const float* Wg = (g == 0) ? Wf : (g == 1) ? Wi : (g == 2) ? Wu : Wo;
    const long long row = sentence[t];
    const float* eb = embed + row * (long long)EMB + chunk * 64;
    const float* wb = Wg + chunk * 256 + w;   // W[k][w] at W[k*4+w], k=chunk*64+...

    float a0 = 0.f, a1 = 0.f, a2 = 0.f, a3 = 0.f;
#pragma unroll
    for (int i = 0; i < 16; ++i) {
        const float4 e4 = *reinterpret_cast<const float4*>(eb + 4 * i);
        a0 = fmaf(e4.x, wb[i * 16 + 0], a0);
        a1 = fmaf(e4.y, wb[i * 16 + 4], a1);
        a2 = fmaf(e4.z, wb[i * 16 + 8], a2);
        a3 = fmaf(e4.w, wb[i * 16 + 12], a3);
    }
    float s = (a0 + a1) + (a2 + a3);

    s += __shfl_xor(s, 16, 64);
    s += __shfl_xor(s, 32, 64);

    if (threadIdx.x < 16) {
        const float* bg = (g == 0) ? bf : (g == 1) ? bi : (g == 2) ? bu : bo;
        const float* pg = (g == 0) ? pf : (g == 1) ? ppi : (g == 2) ? pu : po;
        pre[t * 16 + gw] = (s + bg[w] + pg[w]) * INV2PI;
    }
}

// ---------------- Kernel 2: chunked scan with warmup ------------------------
// blockIdx.x = chunk c; outputs t in [c*CHUNK, (c+1)*CHUNK).
// Chunks start WARM steps early from zero state, CLAMPED at 0 (early chunks
// run their exact prefix from the true init). Worst-case contraction
// rho <= 0.78 => state error at first stored step <= 0.78^48 ~ 7e-6.
// Lane layout identical to the proven serial version: L = g*4+w in each
// 16-lane row, rows replicate -> zero divergence, DPP rows mirror.
__global__ __launch_bounds__(64) void k_scan(
    const float* __restrict__ pre,
    const float* __restrict__ Wf, const float* __restrict__ Wi,
    const float* __restrict__ Wu, const float* __restrict__ Wo,
    float* __restrict__ outs)
{
    const int lane = threadIdx.x & 15;
    const int w = lane & 3, g = lane >> 2;

    const int c       = blockIdx.x;
    const int start   = c * CHUNK;                       // first stored step
    const int t_begin = (start >= WARM) ? (start - WARM) : 0;  // clamped
    const int t_end   = start + CHUNK;
    const int nsteps  = t_end - t_begin;                 // multiple of PFD

    const float* Wg = (g == 0) ? Wf : (g == 1) ? Wi : (g == 2) ? Wu : Wo;
    // h-register r holds hx_{(w+r)&3}; match coefficients accordingly.
    const float c0 = Wg[(EMB + ((w + 0) & 3)) * 4 + w] * INV2PI;
    const float c1 = Wg[(EMB + ((w + 1) & 3)) * 4 + w] * INV2PI;
    const float c2 = Wg[(EMB + ((w + 2) & 3)) * 4 + w] * INV2PI;
    const float c3 = Wg[(EMB + ((w + 3) & 3)) * 4 + w] * INV2PI;

    // f,i,o: sigmoid(q) = 0.5 + 0.5*T(0.5*q); u: tanh(q) = T(q)
    const bool  isU = (g == 2);
    const float alp = isU ? 1.0f : 0.5f;
    const float bet = isU ? 1.0f : 0.5f;
    const float gam = isU ? 0.0f : 0.5f;

    // qlayer subsets: q0=z1z2z3, q1=z0z1, q2=z0z1z2, q3=z0z1z2z3
    const int smask = (w == 0) ? 0xE : (w == 1) ? 0x3 : (w == 2) ? 0x7 : 0xF;
    const bool i0 = (smask >> ((w + 0) & 3)) & 1;
    const bool i1 = (smask >> ((w + 1) & 3)) & 1;
    const bool i2 = (smask >> ((w + 2) & 3)) & 1;
    const bool i3 = (smask >> ((w + 3) & 3)) & 1;

    float buf[PFD];
#pragma unroll
    for (int d = 0; d < PFD; ++d) buf[d] = pre[(t_begin + d) * 16 + lane];

    float h0 = 0.f, h1 = 0.f, h2 = 0.f, h3 = 0.f, cx = 0.f;

    for (int s0 = 0; s0 < nsteps; s0 += PFD) {
#pragma unroll
        for (int d = 0; d < PFD; ++d) {
            const int t = t_begin + s0 + d;
            const float pv = buf[d];
            // prefetch t+PFD (pre padded by PFD*16 floats; tail values unused)
            buf[d] = pre[(t + PFD) * 16 + lane];

            // a in revolutions
            const float a0 = fmaf(h0, c0, pv);
            const float a1 = fmaf(h1, c1, a0);
            const float m2d = h2 * c2;
            const float a2 = fmaf(h3, c3, m2d);
            const float a  = a1 + a2;
            const float z  = cos_rev(a);

            // all four z's of this gate via quad rotations
            const float z1 = fdpp<QR1>(z);
            const float z2 = fdpp<QR2>(z);
            const float z3 = fdpp<QR3>(z);
            const float m0 = i0 ? z  : 1.f;
            const float m1 = i1 ? z1 : 1.f;
            const float m2 = i2 ? z2 : 1.f;
            const float m3 = i3 ? z3 : 1.f;
            const float q  = (m0 * m1) * (m2 * m3);   // in [-1,1]

            // activation via deg-7 odd tanh poly
            const float x   = q * alp;
            const float u   = x * x;
            const float u2p = u * u;
            const float cA  = fmaf(K7, u, K5);
            const float cB  = fmaf(K3, u, K1);
            const float dd  = fmaf(cA, u2p, cB);
            const float v   = x * dd;                 // = T(x)
            const float y   = fmaf(bet, v, gam);

            // gather f,i,u,o across gates (stride 4 in the 16-lane row)
            const float s4  = fdpp<SHL4 >(y);
            const float s8  = fdpp<SHL8 >(y);
            const float s12 = fdpp<SHL12>(y);
            const float r4  = fdpp<SHR4 >(y);
            const float r8  = fdpp<SHR8 >(y);
            const float r12 = fdpp<SHR12>(y);
            const float Fg = (g == 0) ? y   : (g == 1) ? r4 : (g == 2) ? r8 : r12;
            const float Ig = (g == 0) ? s4  : (g == 1) ? y  : (g == 2) ? r4 : r8;
            const float Ug = (g == 0) ? s8  : (g == 1) ? s4 : (g == 2) ? y  : r4;
            const float Og = (g == 0) ? s12 : (g == 1) ? s8 : (g == 2) ? s4 : y;

            cx = fmaf(Fg, cx, Ig * Ug);               // |cx| <= 2.071

            // tanh(cx) via deg-11 odd poly
            const float cu  = cx * cx;
            const float cu2 = cu * cu;
            const float cu4 = cu2 * cu2;
            const float e0  = fmaf(B1, cu, B0);
            const float e1  = fmaf(B3, cu, B2);
            const float e2  = fmaf(B5, cu, B4);
            const float f0  = fmaf(e1, cu2, e0);
            const float f1  = fmaf(e2, cu4, f0);
            const float th  = cx * f1;
            const float h   = Og * th;

            // store only inside the owned window (wave-uniform branch)
            if (t >= start && threadIdx.x < 4) outs[t * 4 + w] = h;

            h0 = h;
            h1 = fdpp<QR1>(h);
            h2 = fdpp<QR2>(h);
            h3 = fdpp<QR3>(h);
        }
    }
}

// ---------------- Kernel 3: logits + log_softmax ----------------------------
__global__ __launch_bounds__(256) void k_out(
    const float* __restrict__ outs, const float* __restrict__ Wt,
    const float* __restrict__ bt, float* __restrict__ out)
{
    const int t = blockIdx.x * blockDim.x + threadIdx.x;
    if (t >= SEQ) return;
    const float h0 = outs[t * 4 + 0], h1 = outs[t * 4 + 1];
    const float h2 = outs[t * 4 + 2], h3 = outs[t * 4 + 3];

    float lg[TAGS];
    float m = -1e30f;
#pragma unroll
    for (int j = 0; j < TAGS; ++j) {
        float v = bt[j];
        v = fmaf(h0, Wt[0 * TAGS + j], v);
        v = fmaf(h1, Wt[1 * TAGS + j], v);
        v = fmaf(h2, Wt[2 * TAGS + j], v);
        v = fmaf(h3, Wt[3 * TAGS + j], v);
        lg[j] = v;
        m = fmaxf(m, v);
    }
    float s = 0.f;
#pragma unroll
    for (int j = 0; j < TAGS; ++j) s += expf(lg[j] - m);
    const float ls = logf(s) + m;
#pragma unroll
    for (int j = 0; j < TAGS; ++j) out[t * TAGS + j] = lg[j] - ls;
}

extern "C" void kernel_launch(void* const* d_in, const int* in_sizes, int n_in,
                              void* d_out, int out_size, void* d_ws, size_t ws_size,
                              hipStream_t stream) {
    const int*   sentence = (const int*)  d_in[0];
    const float* embed    = (const float*)d_in[1];
    const float* Wf  = (const float*)d_in[2];
    const float* bf  = (const float*)d_in[3];
    const float* Wi  = (const float*)d_in[4];
    const float* bi  = (const float*)d_in[5];
    const float* Wu  = (const float*)d_in[6];
    const float* bu  = (const float*)d_in[7];
    const float* Wo  = (const float*)d_in[8];
    const float* bo  = (const float*)d_in[9];
    const float* pf  = (const float*)d_in[10];
    const float* ppi = (const float*)d_in[11];
    const float* pu  = (const float*)d_in[12];
    const float* po  = (const float*)d_in[13];
    const float* Wt  = (const float*)d_in[14];
    const float* bt  = (const float*)d_in[15];

    float* pre  = (float*)d_ws;                    // (SEQ+PFD)*16 floats (padded)
    float* outs = pre + (SEQ + PFD) * 16;          // SEQ*4 floats

    k_pre<<<SEQ, 64, 0, stream>>>(sentence, embed, Wf, bf, Wi, bi, Wu, bu,
                                  Wo, bo, pf, ppi, pu, po, pre);
    k_scan<<<SEQ / CHUNK, 64, 0, stream>>>(pre, Wf, Wi, Wu, Wo, outs);
    k_out<<<(SEQ + 255) / 256, 256, 0, stream>>>(outs, Wt, bt, (float*)d_out);
}

// Round 9
// 33.833 us; speedup vs baseline: 34.2060x; 1.1261x over previous
//
#include <hip/hip_runtime.h>
#include <hip/hip_bf16.h>

#define SEQ   8192
#define EMB   256
#define TAGS  10
#define PFD   8     // prefetch depth in the scan
#define CHUNK 8     // outputs per chunk (one wave each)
#define WARM  40    // warmup steps from zero state (empirical rho<=0.7 -> 6e-7)

static_assert(SEQ % CHUNK == 0, "chunks tile SEQ");
static_assert(CHUNK % PFD == 0 && WARM % PFD == 0, "unroll");

constexpr float INV2PI  = 0.15915494309189535f;   // 1/(2*pi)

// ---------------- DPP helpers (all VALU-speed, no LDS pipe) ----------------
// quad_perm rot1 [1,2,3,0]=0x39, rot2=0x4E, rot3=0x93.
// row_shl:n (0x100+n): lane i reads lane i+n in its 16-lane row.
// row_shr:n (0x110+n): lane i reads lane i-n.  (proven mappings — absmax-exact)
#define QR1   0x39
#define QR2   0x4E
#define QR3   0x93
#define SHL4  0x104
#define SHL8  0x108
#define SHL12 0x10C
#define SHR4  0x114
#define SHR8  0x118
#define SHR12 0x11C

template<int CTRL>
__device__ __forceinline__ float fdpp(float x) {
    return __builtin_bit_cast(float,
        __builtin_amdgcn_update_dpp(0, __builtin_bit_cast(int, x),
                                    CTRL, 0xF, 0xF, true));
}

__device__ __forceinline__ float fract_f(float a) {
#if __has_builtin(__builtin_amdgcn_fractf)
    return __builtin_amdgcn_fractf(a);
#else
    return a - floorf(a);
#endif
}
// a in REVOLUTIONS; v_cos_f32: D = cos(S0 * 2pi), reduce with fract first.
__device__ __forceinline__ float cos_rev(float a) {
    float r = fract_f(a);
#if __has_builtin(__builtin_amdgcn_cosf)
    return __builtin_amdgcn_cosf(r);
#else
    return __cosf(r * 6.2831853071795864f);
#endif
}

// deg-7 odd poly for tanh on [-1,1], max err ~2e-4
#define K1  0.99988000f
#define K3 -0.33064200f
#define K5  0.11945370f
#define K7 -0.02727870f
// deg-11 odd poly for tanh on [-2.15,2.15], max err ~7e-4
#define B0  0.99958010f
#define B1 -0.32717320f
#define B2  0.11471900f
#define B3 -0.03006680f
#define B4  0.00466450f
#define B5 -0.00030650f

// ---------------- Kernel 1: pre[t][g*4+w] = (x@Wg + bg + pg)/(2pi) ----------
// One wave per token. lane = kc(4b)<<2 | g(2b): each lane accumulates a
// float4 over ALL 4 wires of gate g for 16 k's, using contiguous W-row
// float4 loads (W[k][0..3]). 20 VMEM/lane instead of 80 (old scalar-W form).
// Butterfly-reduce over kc (lane bits 2..5), lanes 0..3 write float4.
__global__ __launch_bounds__(64) void k_pre(
    const int*   __restrict__ sentence, const float* __restrict__ embed,
    const float* __restrict__ Wf, const float* __restrict__ bf,
    const float* __restrict__ Wi, const float* __restrict__ bi,
    const float* __restrict__ Wu, const float* __restrict__ bu,
    const float* __restrict__ Wo, const float* __restrict__ bo,
    const float* __restrict__ pf, const float* __restrict__ ppi,
    const float* __restrict__ pu, const float* __restrict__ po,
    float* __restrict__ pre)
{
    const int t  = blockIdx.x;
    const int g  = threadIdx.x & 3;
    const int kc = (threadIdx.x >> 2) & 15;

    const float* Wg = (g == 0) ? Wf : (g == 1) ? Wi : (g == 2) ? Wu : Wo;
    const long long row = sentence[t];
    const float* eb = embed + row * (long long)EMB + kc * 16;
    const float* wb = Wg + kc * 16 * 4;          // W row k at Wg + k*4 (float4)

    float ax = 0.f, ay = 0.f, az = 0.f, aw = 0.f;
#pragma unroll
    for (int i = 0; i < 4; ++i) {
        const float4 e4 = *reinterpret_cast<const float4*>(eb + 4 * i);
        const float4 w0 = *reinterpret_cast<const float4*>(wb + (4 * i + 0) * 4);
        const float4 w1 = *reinterpret_cast<const float4*>(wb + (4 * i + 1) * 4);
        const float4 w2 = *reinterpret_cast<const float4*>(wb + (4 * i + 2) * 4);
        const float4 w3 = *reinterpret_cast<const float4*>(wb + (4 * i + 3) * 4);
        ax = fmaf(e4.x, w0.x, ax); ay = fmaf(e4.x, w0.y, ay);
        az = fmaf(e4.x, w0.z, az); aw = fmaf(e4.x, w0.w, aw);
        ax = fmaf(e4.y, w1.x, ax); ay = fmaf(e4.y, w1.y, ay);
        az = fmaf(e4.y, w1.z, az); aw = fmaf(e4.y, w1.w, aw);
        ax = fmaf(e4.z, w2.x, ax); ay = fmaf(e4.z, w2.y, ay);
        az = fmaf(e4.z, w2.z, az); aw = fmaf(e4.z, w2.w, aw);
        ax = fmaf(e4.w, w3.x, ax); ay = fmaf(e4.w, w3.y, ay);
        az = fmaf(e4.w, w3.z, az); aw = fmaf(e4.w, w3.w, aw);
    }

    // reduce over kc = lane bits 2..5
#pragma unroll
    for (int m = 4; m <= 32; m <<= 1) {
        ax += __shfl_xor(ax, m, 64);
        ay += __shfl_xor(ay, m, 64);
        az += __shfl_xor(az, m, 64);
        aw += __shfl_xor(aw, m, 64);
    }

    if (threadIdx.x < 4) {
        const float* bg = (g == 0) ? bf : (g == 1) ? bi : (g == 2) ? bu : bo;
        const float* pg = (g == 0) ? pf : (g == 1) ? ppi : (g == 2) ? pu : po;
        float4 r;
        r.x = (ax + bg[0] + pg[0]) * INV2PI;
        r.y = (ay + bg[1] + pg[1]) * INV2PI;
        r.z = (az + bg[2] + pg[2]) * INV2PI;
        r.w = (aw + bg[3] + pg[3]) * INV2PI;
        *reinterpret_cast<float4*>(pre + t * 16 + g * 4) = r;
    }
}

// ---------------- Kernel 2: chunked scan with warmup ------------------------
// blockIdx.x = chunk c; outputs t in [c*CHUNK, (c+1)*CHUNK).
// Chunks start WARM steps early from zero state, CLAMPED at 0 (early chunks
// run their exact prefix from the true init). Empirical contraction rho<=0.7
// => state error at first stored step <= ~6e-7 (absmax bit-identical across
// WARM=128/48 at bf16 compare granularity).
// Lane layout identical to the proven serial version: L = g*4+w in each
// 16-lane row, rows replicate -> zero divergence, DPP rows mirror.
__global__ __launch_bounds__(64) void k_scan(
    const float* __restrict__ pre,
    const float* __restrict__ Wf, const float* __restrict__ Wi,
    const float* __restrict__ Wu, const float* __restrict__ Wo,
    float* __restrict__ outs)
{
    const int lane = threadIdx.x & 15;
    const int w = lane & 3, g = lane >> 2;

    const int c       = blockIdx.x;
    const int start   = c * CHUNK;                       // first stored step
    const int t_begin = (start >= WARM) ? (start - WARM) : 0;  // clamped
    const int t_end   = start + CHUNK;
    const int nsteps  = t_end - t_begin;                 // multiple of PFD

    const float* Wg = (g == 0) ? Wf : (g == 1) ? Wi : (g == 2) ? Wu : Wo;
    // h-register r holds hx_{(w+r)&3}; match coefficients accordingly.
    const float c0 = Wg[(EMB + ((w + 0) & 3)) * 4 + w] * INV2PI;
    const float c1 = Wg[(EMB + ((w + 1) & 3)) * 4 + w] * INV2PI;
    const float c2 = Wg[(EMB + ((w + 2) & 3)) * 4 + w] * INV2PI;
    const float c3 = Wg[(EMB + ((w + 3) & 3)) * 4 + w] * INV2PI;

    // f,i,o: sigmoid(q) = 0.5 + 0.5*T(0.5*q); u: tanh(q) = T(q)
    const bool  isU = (g == 2);
    const float alp = isU ? 1.0f : 0.5f;
    const float bet = isU ? 1.0f : 0.5f;
    const float gam = isU ? 0.0f : 0.5f;

    // qlayer subsets: q0=z1z2z3, q1=z0z1, q2=z0z1z2, q3=z0z1z2z3
    const int smask = (w == 0) ? 0xE : (w == 1) ? 0x3 : (w == 2) ? 0x7 : 0xF;
    const bool i0 = (smask >> ((w + 0) & 3)) & 1;
    const bool i1 = (smask >> ((w + 1) & 3)) & 1;
    const bool i2 = (smask >> ((w + 2) & 3)) & 1;
    const bool i3 = (smask >> ((w + 3) & 3)) & 1;

    float buf[PFD];
#pragma unroll
    for (int d = 0; d < PFD; ++d) buf[d] = pre[(t_begin + d) * 16 + lane];

    float h0 = 0.f, h1 = 0.f, h2 = 0.f, h3 = 0.f, cx = 0.f;

    for (int s0 = 0; s0 < nsteps; s0 += PFD) {
#pragma unroll
        for (int d = 0; d < PFD; ++d) {
            const int t = t_begin + s0 + d;
            const float pv = buf[d];
            // prefetch t+PFD (pre padded by PFD*16 floats; tail values unused)
            buf[d] = pre[(t + PFD) * 16 + lane];

            // a in revolutions
            const float a0 = fmaf(h0, c0, pv);
            const float a1 = fmaf(h1, c1, a0);
            const float m2d = h2 * c2;
            const float a2 = fmaf(h3, c3, m2d);
            const float a  = a1 + a2;
            const float z  = cos_rev(a);

            // all four z's of this gate via quad rotations
            const float z1 = fdpp<QR1>(z);
            const float z2 = fdpp<QR2>(z);
            const float z3 = fdpp<QR3>(z);
            const float m0 = i0 ? z  : 1.f;
            const float m1 = i1 ? z1 : 1.f;
            const float m2 = i2 ? z2 : 1.f;
            const float m3 = i3 ? z3 : 1.f;
            const float q  = (m0 * m1) * (m2 * m3);   // in [-1,1]

            // activation via deg-7 odd tanh poly
            const float x   = q * alp;
            const float u   = x * x;
            const float u2p = u * u;
            const float cA  = fmaf(K7, u, K5);
            const float cB  = fmaf(K3, u, K1);
            const float dd  = fmaf(cA, u2p, cB);
            const float v   = x * dd;                 // = T(x)
            const float y   = fmaf(bet, v, gam);

            // gather f,i,u,o across gates (stride 4 in the 16-lane row)
            const float s4  = fdpp<SHL4 >(y);
            const float s8  = fdpp<SHL8 >(y);
            const float s12 = fdpp<SHL12>(y);
            const float r4  = fdpp<SHR4 >(y);
            const float r8  = fdpp<SHR8 >(y);
            const float r12 = fdpp<SHR12>(y);
            const float Fg = (g == 0) ? y   : (g == 1) ? r4 : (g == 2) ? r8 : r12;
            const float Ig = (g == 0) ? s4  : (g == 1) ? y  : (g == 2) ? r4 : r8;
            const float Ug = (g == 0) ? s8  : (g == 1) ? s4 : (g == 2) ? y  : r4;
            const float Og = (g == 0) ? s12 : (g == 1) ? s8 : (g == 2) ? s4 : y;

            cx = fmaf(Fg, cx, Ig * Ug);               // |cx| <= 2.071

            // tanh(cx) via deg-11 odd poly
            const float cu  = cx * cx;
            const float cu2 = cu * cu;
            const float cu4 = cu2 * cu2;
            const float e0  = fmaf(B1, cu, B0);
            const float e1  = fmaf(B3, cu, B2);
            const float e2  = fmaf(B5, cu, B4);
            const float f0  = fmaf(e1, cu2, e0);
            const float f1  = fmaf(e2, cu4, f0);
            const float th  = cx * f1;
            const float h   = Og * th;

            // store only inside the owned window (wave-uniform branch)
            if (t >= start && threadIdx.x < 4) outs[t * 4 + w] = h;

            h0 = h;
            h1 = fdpp<QR1>(h);
            h2 = fdpp<QR2>(h);
            h3 = fdpp<QR3>(h);
        }
    }
}

// ---------------- Kernel 3: logits + log_softmax ----------------------------
__global__ __launch_bounds__(256) void k_out(
    const float* __restrict__ outs, const float* __restrict__ Wt,
    const float* __restrict__ bt, float* __restrict__ out)
{
    const int t = blockIdx.x * blockDim.x + threadIdx.x;
    if (t >= SEQ) return;
    const float h0 = outs[t * 4 + 0], h1 = outs[t * 4 + 1];
    const float h2 = outs[t * 4 + 2], h3 = outs[t * 4 + 3];

    float lg[TAGS];
    float m = -1e30f;
#pragma unroll
    for (int j = 0; j < TAGS; ++j) {
        float v = bt[j];
        v = fmaf(h0, Wt[0 * TAGS + j], v);
        v = fmaf(h1, Wt[1 * TAGS + j], v);
        v = fmaf(h2, Wt[2 * TAGS + j], v);
        v = fmaf(h3, Wt[3 * TAGS + j], v);
        lg[j] = v;
        m = fmaxf(m, v);
    }
    float s = 0.f;
#pragma unroll
    for (int j = 0; j < TAGS; ++j) s += expf(lg[j] - m);
    const float ls = logf(s) + m;
#pragma unroll
    for (int j = 0; j < TAGS; ++j) out[t * TAGS + j] = lg[j] - ls;
}

extern "C" void kernel_launch(void* const* d_in, const int* in_sizes, int n_in,
                              void* d_out, int out_size, void* d_ws, size_t ws_size,
                              hipStream_t stream) {
    const int*   sentence = (const int*)  d_in[0];
    const float* embed    = (const float*)d_in[1];
    const float* Wf  = (const float*)d_in[2];
    const float* bf  = (const float*)d_in[3];
    const float* Wi  = (const float*)d_in[4];
    const float* bi  = (const float*)d_in[5];
    const float* Wu  = (const float*)d_in[6];
    const float* bu  = (const float*)d_in[7];
    const float* Wo  = (const float*)d_in[8];
    const float* bo  = (const float*)d_in[9];
    const float* pf  = (const float*)d_in[10];
    const float* ppi = (const float*)d_in[11];
    const float* pu  = (const float*)d_in[12];
    const float* po  = (const float*)d_in[13];
    const float* Wt  = (const float*)d_in[14];
    const float* bt  = (const float*)d_in[15];

    float* pre  = (float*)d_ws;                    // (SEQ+PFD)*16 floats (padded)
    float* outs = pre + (SEQ + PFD) * 16;          // SEQ*4 floats

    k_pre<<<SEQ, 64, 0, stream>>>(sentence, embed, Wf, bf, Wi, bi, Wu, bu,
                                  Wo, bo, pf, ppi, pu, po, pre);
    k_scan<<<SEQ / CHUNK, 64, 0, stream>>>(pre, Wf, Wi, Wu, Wo, outs);
    k_out<<<(SEQ + 255) / 256, 256, 0, stream>>>(outs, Wt, bt, (float*)d_out);
}